// Round 10
// baseline (168.616 us; speedup 1.0000x reference)
//
#include <hip/hip_runtime.h>
#include <hip/hip_bf16.h>

// IndexedLinear: out[n] = x[n] @ W[idx[n]]
// N=262144, D_IN=D_OUT=256, NUM_TYPES=16, fp32 in/out.
// Round 8: DEPTH-2 stage pipeline (3 LDS buffers, stage t+2 at iter t).
// Rounds 2-7 all pinned at ~2.5 TB/s: with 1-deep prefetch, outstanding
// bytes = burst x latency/period self-limits to ~latency-worth. Depth-2
// gives loads ~1.5 periods to land -> period becomes BW-limited.
// 8-wave blocks, 32 cols/wave: W panel = 64 VGPR, 16 waves/CU.

#define NTYPES 16
#define TROWS 16
#define NBUF 3
#define GRID_BLOCKS 512

typedef __bf16 bf16x8 __attribute__((ext_vector_type(8)));
typedef float f32x4 __attribute__((ext_vector_type(4)));

static __device__ __forceinline__ unsigned int f2bf_pk(float a, float b) {
  unsigned int ua = __float_as_uint(a);
  unsigned int ub = __float_as_uint(b);
  ua = (ua + 0x7FFFu + ((ua >> 16) & 1u)) >> 16;  // RNE f32->bf16
  ub = (ub + 0x7FFFu + ((ub >> 16) & 1u)) >> 16;
  return ua | (ub << 16);
}

static __device__ __forceinline__ unsigned int cvtpk(float a, float b) {
  unsigned int r;
  asm("v_cvt_pk_bf16_f32 %0, %1, %2" : "=v"(r) : "v"(a), "v"(b));
  return r;
}

static __device__ __forceinline__ void load16_lds(const float* g, float* l) {
  __builtin_amdgcn_global_load_lds(
      (const __attribute__((address_space(1))) unsigned int*)g,
      (__attribute__((address_space(3))) unsigned int*)l, 16, 0, 0);
}

// meta layout (unsigned int):
// [0..15] cnt | [16..31] off | [32..47] cursor | [48..64] tileStart prefix

__global__ void zero_meta_kernel(unsigned int* meta) {
  if (threadIdx.x < 128) meta[threadIdx.x] = 0;
}

__global__ void hist_kernel(const int* __restrict__ idx, int N,
                            unsigned int* __restrict__ meta) {
  __shared__ unsigned int h[NTYPES];
  if (threadIdx.x < NTYPES) h[threadIdx.x] = 0;
  __syncthreads();
  for (int n = blockIdx.x * 256 + threadIdx.x; n < N; n += gridDim.x * 256)
    atomicAdd(&h[idx[n] & 15], 1u);
  __syncthreads();
  if (threadIdx.x < NTYPES) atomicAdd(&meta[threadIdx.x], h[threadIdx.x]);
}

__global__ void prefix_kernel(unsigned int* meta) {
  if (threadIdx.x == 0) {
    unsigned int o = 0, ts = 0;
    for (int t = 0; t < NTYPES; t++) {
      meta[16 + t] = o;
      meta[32 + t] = o;
      meta[48 + t] = ts;
      o += meta[t];
      ts += (meta[t] + (TROWS - 1)) / TROWS;
    }
    meta[64] = ts;
  }
}

__global__ void tiles_kernel(const unsigned int* __restrict__ meta,
                             uint2* __restrict__ desc, int maxTiles) {
  __shared__ unsigned int ts[17], offs[16], cnts[16];
  if (threadIdx.x < 17) ts[threadIdx.x] = meta[48 + threadIdx.x];
  if (threadIdx.x < 16) {
    offs[threadIdx.x] = meta[16 + threadIdx.x];
    cnts[threadIdx.x] = meta[threadIdx.x];
  }
  __syncthreads();
  int tile = blockIdx.x * 256 + threadIdx.x;
  if (tile >= maxTiles) return;
  uint2 d = make_uint2(0u, 0u);
  if ((unsigned)tile < ts[16]) {
    int t = 0;
    while ((unsigned)tile >= ts[t + 1]) t++;
    unsigned int rowbase = offs[t] + ((unsigned)tile - ts[t]) * TROWS;
    unsigned int rem = offs[t] + cnts[t] - rowbase;
    unsigned int nrows = rem < (unsigned)TROWS ? rem : (unsigned)TROWS;
    d = make_uint2(rowbase, (unsigned)t | (nrows << 8));
  }
  desc[tile] = d;
}

__global__ void scatter_kernel(const int* __restrict__ idx, int N,
                               unsigned int* __restrict__ meta,
                               int* __restrict__ perm) {
  __shared__ unsigned int h[NTYPES];
  __shared__ unsigned int base[NTYPES];
  int b0 = blockIdx.x * 4096;
  if (threadIdx.x < NTYPES) h[threadIdx.x] = 0;
  __syncthreads();
  unsigned int lr[16];
  int tt[16];
#pragma unroll
  for (int i = 0; i < 16; i++) {
    int n = b0 + i * 256 + threadIdx.x;
    int t = (n < N) ? (idx[n] & 15) : 0;
    tt[i] = t;
    lr[i] = (n < N) ? atomicAdd(&h[t], 1u) : 0u;
  }
  __syncthreads();
  if (threadIdx.x < NTYPES)
    base[threadIdx.x] = atomicAdd(&meta[32 + threadIdx.x], h[threadIdx.x]);
  __syncthreads();
#pragma unroll
  for (int i = 0; i < 16; i++) {
    int n = b0 + i * 256 + threadIdx.x;
    if (n < N) perm[base[tt[i]] + lr[i]] = n;
  }
}

// Pack W[t][k][c] (fp32) -> Wp[(t*8+kblk)*256 + c][ks] (bf16).
__global__ void packW_kernel(const float* __restrict__ W,
                             unsigned short* __restrict__ Wp) {
  int id = blockIdx.x * 256 + threadIdx.x;  // (t*8+kblk)*256 + c
  int c = id & 255;
  int tk = id >> 8;
  const float* src = W + (size_t)tk * 32 * 256 + c;
  unsigned int buf[16];
#pragma unroll
  for (int p = 0; p < 16; p++)
    buf[p] = f2bf_pk(src[(2 * p) * 256], src[(2 * p + 1) * 256]);
  uint4* d4 = (uint4*)(Wp + (size_t)id * 32);
#pragma unroll
  for (int p = 0; p < 4; p++)
    d4[p] = make_uint4(buf[4 * p], buf[4 * p + 1], buf[4 * p + 2], buf[4 * p + 3]);
}

// Depth-2 pipelined grouped GEMM.
// 8 waves x 32 cols each; tile = 16 rows x 256 cols. 3 LDS buffers:
// iter t computes buf[t%3], stages tile t+2 into buf[(t+2)%3].
// Per-wave vmem queue/iter: stage 2 + perm 1 + desc 1 + stores 8 = 12.
// Barrier: s_waitcnt vmcnt(12) -> everything from earlier iterations
// retired (stage(t+1) landed, stores(t-1) acked) while this iteration's
// 12 ops stay in flight. Over-wait-safe under any issue reordering.
__global__ __launch_bounds__(512, 2) void gemm_kernel(
    const float* __restrict__ x, const unsigned short* __restrict__ Wp,
    const int* __restrict__ perm, const uint2* __restrict__ desc,
    float* __restrict__ out, float* __restrict__ dump, int maxTiles) {
  __shared__ float ldsx[NBUF][TROWS * 256];  // 3 x 16 KiB
  __shared__ int permS[NBUF][TROWS];

  int tpb = maxTiles / GRID_BLOCKS;
  int rem = maxTiles - tpb * GRID_BLOCKS;
  int b = blockIdx.x;
  int base = b * tpb + (b < rem ? b : rem);
  int cnt = tpb + (b < rem ? 1 : 0);
  if (cnt <= 0) return;

  int tid = threadIdx.x;
  int l = tid & 63, w = tid >> 6;  // 8 waves, wave w owns cols [w*32,w*32+32)
  int lm = l & 15, lh = l >> 4;
  int clampT = maxTiles - 1;
  int myrow = 2 * w + (l & 1);  // row this lane's perm prefetch covers

  uint2 d0, d1, d2, d3;
  {
    int j;
    j = base + 0; d0 = desc[j <= clampT ? j : clampT];
    j = base + 1; d1 = desc[j <= clampT ? j : clampT];
    j = base + 2; d2 = desc[j <= clampT ? j : clampT];
    j = base + 3; d3 = desc[j <= clampT ? j : clampT];
  }

  int pr0 = 0, pr1 = 0, pr2 = 0;
  { int nr = (int)(d0.y >> 8); if (myrow < nr) pr0 = perm[d0.x + myrow]; }
  if (cnt > 1) { int nr = (int)(d1.y >> 8); if (myrow < nr) pr1 = perm[d1.x + myrow]; }
  if (cnt > 2) { int nr = (int)(d2.y >> 8); if (myrow < nr) pr2 = perm[d2.x + myrow]; }

  // prologue: stage tiles base+0 -> buf0, base+1 -> buf1
  if (l < 2) permS[0][myrow] = pr0;
#pragma unroll
  for (int j = 0; j < 2; ++j) {
    int prj = __shfl(pr0, j);
    int row = 2 * w + j;
    load16_lds(x + (size_t)prj * 256 + ((l ^ (row & 7)) << 2),
               &ldsx[0][row * 256]);
  }
  if (cnt > 1) {
    if (l < 2) permS[1][myrow] = pr1;
#pragma unroll
    for (int j = 0; j < 2; ++j) {
      int prj = __shfl(pr1, j);
      int row = 2 * w + j;
      load16_lds(x + (size_t)prj * 256 + ((l ^ (row & 7)) << 2),
                 &ldsx[1][row * 256]);
    }
  }
  __syncthreads();  // one-time full drain: buf0/buf1 landed

  int bc = 0;       // compute buffer
  int tCached = -1;
  bf16x8 wfr[16];   // W panel: [kk*2+fn], 64 VGPR, reload on type change
  const uint4* Wp4 = (const uint4*)Wp;
  float* dumpP = dump + (size_t)tid * 16;  // 512 thr x 16 floats = 32 KB

  for (int it = 0; it < cnt; ++it) {
    int nrowsC = (int)(d0.y >> 8);
    int tC = (int)(d0.y & 15u);
    int bs = bc + 2; if (bs >= NBUF) bs -= NBUF;  // stage buffer

    // A. stage tile it+2 into buf bs (in flight for ~1.5 iterations)
    if (it + 2 < cnt) {
      if (l < 2) permS[bs][myrow] = pr2;
#pragma unroll
      for (int j = 0; j < 2; ++j) {
        int prj = __shfl(pr2, j);
        int row = 2 * w + j;
        load16_lds(x + (size_t)prj * 256 + ((l ^ (row & 7)) << 2),
                   &ldsx[bs][row * 256]);
      }
    }
    // B. prefetch perm for it+3, desc for it+4
    int pr3 = 0;
    if (it + 3 < cnt) {
      int nr = (int)(d3.y >> 8);
      if (myrow < nr) pr3 = perm[d3.x + myrow];
    }
    uint2 d4;
    { int j4 = base + it + 4; d4 = desc[j4 <= clampT ? j4 : clampT]; }

    // C. W panel reload on type change (rare; uniform branch; over-waits
    // once at the next barrier -- safe)
    if (tC != tCached) {
      tCached = tC;
      const uint4* Wt = Wp4 + (size_t)tC * 8 * 256 * 4;
#pragma unroll
      for (int kk = 0; kk < 8; kk++)
#pragma unroll
        for (int fn = 0; fn < 2; fn++)
          wfr[kk * 2 + fn] = __builtin_bit_cast(
              bf16x8,
              Wt[(size_t)(kk * 256 + w * 32 + fn * 16 + lm) * 4 + lh]);
    }

    // D. K-loop: pure LDS + VALU + MFMA
    f32x4 acc[2];
    acc[0] = (f32x4){0.f, 0.f, 0.f, 0.f};
    acc[1] = (f32x4){0.f, 0.f, 0.f, 0.f};

#pragma unroll
    for (int kk = 0; kk < 8; kk++) {
      const float4* rowp = (const float4*)&ldsx[bc][lm * 256];
      int c0 = kk * 8 + lh * 2;
      int s = lm & 7;
      float4 f0 = rowp[c0 ^ s];
      float4 f1 = rowp[(c0 + 1) ^ s];
      uint4 v;
      v.x = cvtpk(f0.x, f0.y);
      v.y = cvtpk(f0.z, f0.w);
      v.z = cvtpk(f1.x, f1.y);
      v.w = cvtpk(f1.z, f1.w);
      bf16x8 a = __builtin_bit_cast(bf16x8, v);
      acc[0] = __builtin_amdgcn_mfma_f32_16x16x32_bf16(a, wfr[kk * 2 + 0],
                                                       acc[0], 0, 0, 0);
      acc[1] = __builtin_amdgcn_mfma_f32_16x16x32_bf16(a, wfr[kk * 2 + 1],
                                                       acc[1], 0, 0, 0);
    }

    // E. stores: 8 per wave, branchless dump for invalid rows (constant
    // queue shape). D layout col=lane&15, row=(lane>>4)*4+r_
#pragma unroll
    for (int r_ = 0; r_ < 4; r_++) {
      int rit = lh * 4 + r_;
      bool valid = rit < nrowsC;
      int grow = permS[bc][rit];
      float* orow = out + (size_t)grow * 256 + w * 32 + lm;
#pragma unroll
      for (int fn = 0; fn < 2; fn++) {
        float* p = valid ? orow + fn * 16 : dumpP + fn;
        *p = acc[fn][r_];
      }
    }

    // F. counted barrier: this iter's 12 vmem ops stay in flight; all
    // earlier iterations' ops (incl. stage(t+1)) provably retired.
    asm volatile("s_waitcnt vmcnt(12) lgkmcnt(0)\n\ts_barrier" ::: "memory");
    __builtin_amdgcn_sched_barrier(0);

    bc = bc + 1 == NBUF ? 0 : bc + 1;
    d0 = d1; d1 = d2; d2 = d3; d3 = d4;
    pr2 = pr3;
  }
}

extern "C" void kernel_launch(void* const* d_in, const int* in_sizes, int n_in,
                              void* d_out, int out_size, void* d_ws,
                              size_t ws_size, hipStream_t stream) {
  const float* x = (const float*)d_in[0];
  const int* idx = (const int*)d_in[1];
  const float* W = (const float*)d_in[2];
  float* out = (float*)d_out;
  int N = in_sizes[0] / 256;
  int maxTiles = N / TROWS + NTYPES;

  // ws: meta 512B | dump 64KB | desc maxTiles*8 | perm N*4 | Wp 2MB
  unsigned int* meta = (unsigned int*)d_ws;
  float* dump = (float*)((char*)d_ws + 512);
  uint2* desc = (uint2*)((char*)d_ws + 512 + 65536);
  int* perm = (int*)((char*)d_ws + 512 + 65536 + (size_t)maxTiles * 8);
  unsigned short* Wp =
      (unsigned short*)((char*)d_ws + 512 + 65536 + (size_t)maxTiles * 8 +
                        (size_t)N * 4);

  zero_meta_kernel<<<1, 128, 0, stream>>>(meta);
  hist_kernel<<<256, 256, 0, stream>>>(idx, N, meta);
  prefix_kernel<<<1, 64, 0, stream>>>(meta);
  packW_kernel<<<128, 256, 0, stream>>>(W, Wp);
  tiles_kernel<<<(maxTiles + 255) / 256, 256, 0, stream>>>(meta, desc,
                                                           maxTiles);
  int nScatter = (N + 4095) / 4096;
  scatter_kernel<<<nScatter, 256, 0, stream>>>(idx, N, meta, perm);

  gemm_kernel<<<GRID_BLOCKS, 512, 0, stream>>>(x, Wp, perm, desc, out, dump,
                                               maxTiles);
}

// Round 11
// 167.385 us; speedup vs baseline: 1.0074x; 1.0074x over previous
//
#include <hip/hip_runtime.h>
#include <hip/hip_bf16.h>

// IndexedLinear: out[n] = x[n] @ W[idx[n]]
// N=262144, D_IN=D_OUT=256, NUM_TYPES=16, fp32 in/out.
// Round 9: DEPTH-3 stage pipeline (4 LDS buffers, stage t+3 at iter t),
// barrier = s_waitcnt vmcnt(28): keeps ~3 stages (48 KB/block) in flight
// across every barrier. R8 accounting: in-flight was only ~2.7 KB/CU
// (stage landed in 2K of a 24K-cyc iteration; vmcnt(12) retired it at the
// barrier) -> 0.87 TB/s fetch, exactly Little's law. fillBuffer at 6.5 TB/s
// proves the HBM system is not the wall.

#define NTYPES 16
#define TROWS 16
#define NBUF 4
#define GRID_BLOCKS 512

typedef __bf16 bf16x8 __attribute__((ext_vector_type(8)));
typedef float f32x4 __attribute__((ext_vector_type(4)));

static __device__ __forceinline__ unsigned int f2bf_pk(float a, float b) {
  unsigned int ua = __float_as_uint(a);
  unsigned int ub = __float_as_uint(b);
  ua = (ua + 0x7FFFu + ((ua >> 16) & 1u)) >> 16;  // RNE f32->bf16
  ub = (ub + 0x7FFFu + ((ub >> 16) & 1u)) >> 16;
  return ua | (ub << 16);
}

static __device__ __forceinline__ unsigned int cvtpk(float a, float b) {
  unsigned int r;
  asm("v_cvt_pk_bf16_f32 %0, %1, %2" : "=v"(r) : "v"(a), "v"(b));
  return r;
}

static __device__ __forceinline__ void load16_lds(const float* g, float* l) {
  __builtin_amdgcn_global_load_lds(
      (const __attribute__((address_space(1))) unsigned int*)g,
      (__attribute__((address_space(3))) unsigned int*)l, 16, 0, 0);
}

// meta layout (unsigned int):
// [0..15] cnt | [16..31] off | [32..47] cursor | [48..64] tileStart prefix

__global__ void zero_meta_kernel(unsigned int* meta) {
  if (threadIdx.x < 128) meta[threadIdx.x] = 0;
}

__global__ void hist_kernel(const int* __restrict__ idx, int N,
                            unsigned int* __restrict__ meta) {
  __shared__ unsigned int h[NTYPES];
  if (threadIdx.x < NTYPES) h[threadIdx.x] = 0;
  __syncthreads();
  for (int n = blockIdx.x * 256 + threadIdx.x; n < N; n += gridDim.x * 256)
    atomicAdd(&h[idx[n] & 15], 1u);
  __syncthreads();
  if (threadIdx.x < NTYPES) atomicAdd(&meta[threadIdx.x], h[threadIdx.x]);
}

__global__ void prefix_kernel(unsigned int* meta) {
  if (threadIdx.x == 0) {
    unsigned int o = 0, ts = 0;
    for (int t = 0; t < NTYPES; t++) {
      meta[16 + t] = o;
      meta[32 + t] = o;
      meta[48 + t] = ts;
      o += meta[t];
      ts += (meta[t] + (TROWS - 1)) / TROWS;
    }
    meta[64] = ts;
  }
}

__global__ void tiles_kernel(const unsigned int* __restrict__ meta,
                             uint2* __restrict__ desc, int maxTiles) {
  __shared__ unsigned int ts[17], offs[16], cnts[16];
  if (threadIdx.x < 17) ts[threadIdx.x] = meta[48 + threadIdx.x];
  if (threadIdx.x < 16) {
    offs[threadIdx.x] = meta[16 + threadIdx.x];
    cnts[threadIdx.x] = meta[threadIdx.x];
  }
  __syncthreads();
  int tile = blockIdx.x * 256 + threadIdx.x;
  if (tile >= maxTiles) return;
  uint2 d = make_uint2(0u, 0u);
  if ((unsigned)tile < ts[16]) {
    int t = 0;
    while ((unsigned)tile >= ts[t + 1]) t++;
    unsigned int rowbase = offs[t] + ((unsigned)tile - ts[t]) * TROWS;
    unsigned int rem = offs[t] + cnts[t] - rowbase;
    unsigned int nrows = rem < (unsigned)TROWS ? rem : (unsigned)TROWS;
    d = make_uint2(rowbase, (unsigned)t | (nrows << 8));
  }
  desc[tile] = d;
}

__global__ void scatter_kernel(const int* __restrict__ idx, int N,
                               unsigned int* __restrict__ meta,
                               int* __restrict__ perm) {
  __shared__ unsigned int h[NTYPES];
  __shared__ unsigned int base[NTYPES];
  int b0 = blockIdx.x * 4096;
  if (threadIdx.x < NTYPES) h[threadIdx.x] = 0;
  __syncthreads();
  unsigned int lr[16];
  int tt[16];
#pragma unroll
  for (int i = 0; i < 16; i++) {
    int n = b0 + i * 256 + threadIdx.x;
    int t = (n < N) ? (idx[n] & 15) : 0;
    tt[i] = t;
    lr[i] = (n < N) ? atomicAdd(&h[t], 1u) : 0u;
  }
  __syncthreads();
  if (threadIdx.x < NTYPES)
    base[threadIdx.x] = atomicAdd(&meta[32 + threadIdx.x], h[threadIdx.x]);
  __syncthreads();
#pragma unroll
  for (int i = 0; i < 16; i++) {
    int n = b0 + i * 256 + threadIdx.x;
    if (n < N) perm[base[tt[i]] + lr[i]] = n;
  }
}

// Pack W[t][k][c] (fp32) -> Wp[(t*8+kblk)*256 + c][ks] (bf16).
__global__ void packW_kernel(const float* __restrict__ W,
                             unsigned short* __restrict__ Wp) {
  int id = blockIdx.x * 256 + threadIdx.x;  // (t*8+kblk)*256 + c
  int c = id & 255;
  int tk = id >> 8;
  const float* src = W + (size_t)tk * 32 * 256 + c;
  unsigned int buf[16];
#pragma unroll
  for (int p = 0; p < 16; p++)
    buf[p] = f2bf_pk(src[(2 * p) * 256], src[(2 * p + 1) * 256]);
  uint4* d4 = (uint4*)(Wp + (size_t)id * 32);
#pragma unroll
  for (int p = 0; p < 4; p++)
    d4[p] = make_uint4(buf[4 * p], buf[4 * p + 1], buf[4 * p + 2], buf[4 * p + 3]);
}

// Depth-3 pipelined grouped GEMM.
// 8 waves x 32 cols; tile = 16 rows x 256 cols. 4 LDS buffers: iter t
// computes buf[t%4], stages tile t+3 into buf[(t+3)%4].
// Per-wave vmem/iter (certain): 2 stage + 8 stores (+perm +desc if vmem).
// Barrier wait vmcnt(28): 28 = stores(3 iters)=24 + stages(2 iters)=4 ->
// guarantees the stage needed NEXT iteration has retired, while up to 3
// stages (48 KB/block) remain in flight. Robust whether perm/desc go
// through vmem or SMEM (extra ops only make the wait stronger).
__global__ __launch_bounds__(512, 2) void gemm_kernel(
    const float* __restrict__ x, const unsigned short* __restrict__ Wp,
    const int* __restrict__ perm, const uint2* __restrict__ desc,
    float* __restrict__ out, float* __restrict__ dump, int maxTiles) {
  __shared__ float ldsx[NBUF][TROWS * 256];  // 4 x 16 KiB
  __shared__ int permS[NBUF][TROWS];

  int tpb = maxTiles / GRID_BLOCKS;
  int rem = maxTiles - tpb * GRID_BLOCKS;
  int b = blockIdx.x;
  int base = b * tpb + (b < rem ? b : rem);
  int cnt = tpb + (b < rem ? 1 : 0);
  if (cnt <= 0) return;

  int tid = threadIdx.x;
  int l = tid & 63, w = tid >> 6;  // 8 waves, wave w owns cols [w*32,w*32+32)
  int lm = l & 15, lh = l >> 4;
  int clampT = maxTiles - 1;
  int myrow = 2 * w + (l & 1);

  uint2 d0, d1, d2, d3, d4;
  {
    int j;
    j = base + 0; d0 = desc[j <= clampT ? j : clampT];
    j = base + 1; d1 = desc[j <= clampT ? j : clampT];
    j = base + 2; d2 = desc[j <= clampT ? j : clampT];
    j = base + 3; d3 = desc[j <= clampT ? j : clampT];
    j = base + 4; d4 = desc[j <= clampT ? j : clampT];
  }

  int pr0 = 0, pr1 = 0, pr2 = 0, prStage = 0;
  { int nr = (int)(d0.y >> 8); if (myrow < nr) pr0 = perm[d0.x + myrow]; }
  if (cnt > 1) { int nr = (int)(d1.y >> 8); if (myrow < nr) pr1 = perm[d1.x + myrow]; }
  if (cnt > 2) { int nr = (int)(d2.y >> 8); if (myrow < nr) pr2 = perm[d2.x + myrow]; }
  if (cnt > 3) { int nr = (int)(d3.y >> 8); if (myrow < nr) prStage = perm[d3.x + myrow]; }

  // prologue: stage tiles 0,1,2 into bufs 0,1,2
  if (l < 2) permS[0][myrow] = pr0;
#pragma unroll
  for (int j = 0; j < 2; ++j) {
    int prj = __shfl(pr0, j);
    int row = 2 * w + j;
    load16_lds(x + (size_t)prj * 256 + ((l ^ (row & 7)) << 2),
               &ldsx[0][row * 256]);
  }
  if (cnt > 1) {
    if (l < 2) permS[1][myrow] = pr1;
#pragma unroll
    for (int j = 0; j < 2; ++j) {
      int prj = __shfl(pr1, j);
      int row = 2 * w + j;
      load16_lds(x + (size_t)prj * 256 + ((l ^ (row & 7)) << 2),
                 &ldsx[1][row * 256]);
    }
  }
  if (cnt > 2) {
    if (l < 2) permS[2][myrow] = pr2;
#pragma unroll
    for (int j = 0; j < 2; ++j) {
      int prj = __shfl(pr2, j);
      int row = 2 * w + j;
      load16_lds(x + (size_t)prj * 256 + ((l ^ (row & 7)) << 2),
                 &ldsx[2][row * 256]);
    }
  }
  __syncthreads();  // one-time full drain: bufs 0-2 landed

  int tCached = -1;
  bf16x8 wfr[16];  // W panel: [kk*2+fn], 64 VGPR, reload on type change
  const uint4* Wp4 = (const uint4*)Wp;
  float* dumpP = dump + (size_t)tid * 16;

  for (int it = 0; it < cnt; ++it) {
    int bc = it & (NBUF - 1);
    int bs = (it + 3) & (NBUF - 1);
    int nrowsC = (int)(d0.y >> 8);
    int tC = (int)(d0.y & 15u);

    // A. stage tile it+3 into buf bs (3 stages in flight in steady state)
    if (it + 3 < cnt) {
      if (l < 2) permS[bs][myrow] = prStage;
#pragma unroll
      for (int j = 0; j < 2; ++j) {
        int prj = __shfl(prStage, j);
        int row = 2 * w + j;
        load16_lds(x + (size_t)prj * 256 + ((l ^ (row & 7)) << 2),
                   &ldsx[bs][row * 256]);
      }
    }
    // B. prefetch perm for tile it+4, desc for it+5
    int prNext = 0;
    if (it + 4 < cnt) {
      int nr = (int)(d4.y >> 8);
      if (myrow < nr) prNext = perm[d4.x + myrow];
    }
    uint2 d5;
    { int j5 = base + it + 5; d5 = desc[j5 <= clampT ? j5 : clampT]; }

    // C. W panel reload on type change (rare; uniform branch)
    if (tC != tCached) {
      tCached = tC;
      const uint4* Wt = Wp4 + (size_t)tC * 8 * 256 * 4;
#pragma unroll
      for (int kk = 0; kk < 8; kk++)
#pragma unroll
        for (int fn = 0; fn < 2; fn++)
          wfr[kk * 2 + fn] = __builtin_bit_cast(
              bf16x8,
              Wt[(size_t)(kk * 256 + w * 32 + fn * 16 + lm) * 4 + lh]);
    }

    // D. K-loop: pure LDS + VALU + MFMA
    f32x4 acc[2];
    acc[0] = (f32x4){0.f, 0.f, 0.f, 0.f};
    acc[1] = (f32x4){0.f, 0.f, 0.f, 0.f};

#pragma unroll
    for (int kk = 0; kk < 8; kk++) {
      const float4* rowp = (const float4*)&ldsx[bc][lm * 256];
      int c0 = kk * 8 + lh * 2;
      int s = lm & 7;
      float4 f0 = rowp[c0 ^ s];
      float4 f1 = rowp[(c0 + 1) ^ s];
      uint4 v;
      v.x = cvtpk(f0.x, f0.y);
      v.y = cvtpk(f0.z, f0.w);
      v.z = cvtpk(f1.x, f1.y);
      v.w = cvtpk(f1.z, f1.w);
      bf16x8 a = __builtin_bit_cast(bf16x8, v);
      acc[0] = __builtin_amdgcn_mfma_f32_16x16x32_bf16(a, wfr[kk * 2 + 0],
                                                       acc[0], 0, 0, 0);
      acc[1] = __builtin_amdgcn_mfma_f32_16x16x32_bf16(a, wfr[kk * 2 + 1],
                                                       acc[1], 0, 0, 0);
    }

    // E. stores: 8 per wave, branchless dump for invalid rows.
    // D layout col=lane&15, row=(lane>>4)*4+r_
#pragma unroll
    for (int r_ = 0; r_ < 4; r_++) {
      int rit = lh * 4 + r_;
      bool valid = rit < nrowsC;
      int grow = permS[bc][rit];
      float* orow = out + (size_t)grow * 256 + w * 32 + lm;
#pragma unroll
      for (int fn = 0; fn < 2; fn++) {
        float* p = valid ? orow + fn * 16 : dumpP + fn;
        *p = acc[fn][r_];
      }
    }

    // F. counted barrier: vmcnt(28) = stores(24)+stages(4) newer than the
    // stage needed next iteration -> it has retired; up to 3 stages stay
    // in flight. lgkmcnt(0) drains permS ds_writes before s_barrier.
    asm volatile("s_waitcnt vmcnt(28) lgkmcnt(0)\n\ts_barrier" ::: "memory");

    d0 = d1; d1 = d2; d2 = d3; d3 = d4; d4 = d5;
    prStage = prNext;
  }
}

extern "C" void kernel_launch(void* const* d_in, const int* in_sizes, int n_in,
                              void* d_out, int out_size, void* d_ws,
                              size_t ws_size, hipStream_t stream) {
  const float* x = (const float*)d_in[0];
  const int* idx = (const int*)d_in[1];
  const float* W = (const float*)d_in[2];
  float* out = (float*)d_out;
  int N = in_sizes[0] / 256;
  int maxTiles = N / TROWS + NTYPES;

  // ws: meta 512B | dump 64KB | desc maxTiles*8 | perm N*4 | Wp 2MB
  unsigned int* meta = (unsigned int*)d_ws;
  float* dump = (float*)((char*)d_ws + 512);
  uint2* desc = (uint2*)((char*)d_ws + 512 + 65536);
  int* perm = (int*)((char*)d_ws + 512 + 65536 + (size_t)maxTiles * 8);
  unsigned short* Wp =
      (unsigned short*)((char*)d_ws + 512 + 65536 + (size_t)maxTiles * 8 +
                        (size_t)N * 4);

  zero_meta_kernel<<<1, 128, 0, stream>>>(meta);
  hist_kernel<<<256, 256, 0, stream>>>(idx, N, meta);
  prefix_kernel<<<1, 64, 0, stream>>>(meta);
  packW_kernel<<<128, 256, 0, stream>>>(W, Wp);
  tiles_kernel<<<(maxTiles + 255) / 256, 256, 0, stream>>>(meta, desc,
                                                           maxTiles);
  int nScatter = (N + 4095) / 4096;
  scatter_kernel<<<nScatter, 256, 0, stream>>>(idx, N, meta, perm);

  gemm_kernel<<<GRID_BLOCKS, 512, 0, stream>>>(x, Wp, perm, desc, out, dump,
                                               maxTiles);
}

// Round 12
// 140.271 us; speedup vs baseline: 1.2021x; 1.1933x over previous
//
#include <hip/hip_runtime.h>
#include <hip/hip_bf16.h>

// IndexedLinear: out[n] = x[n] @ W[idx[n]]
// N=262144, D_IN=D_OUT=256, NUM_TYPES=16, fp32 in/out.
// Round 10: BARRIER-FREE per-wave streaming. 6 barrier-phased variants all
// pinned at ~162us / 2.5 TB/s with every pipe idle -> the block-wide barrier
// topology itself serializes. Now: 256 blocks (1/CU), one TYPE per block,
// W panel (128 KB bf16) in LDS in conflict-free frag layout; 8 waves per
// block free-run independent 16-row tiles: x -> registers directly in
// a-frag layout (no LDS for x, no shuffles), per-wave vmcnt-counted
// software pipeline, zero s_barrier in the steady loop.

#define NTYPES 16
#define GRID_BLOCKS 256

typedef __bf16 bf16x8 __attribute__((ext_vector_type(8)));
typedef float f32x4 __attribute__((ext_vector_type(4)));

static __device__ __forceinline__ unsigned int f2bf_pk(float a, float b) {
  unsigned int ua = __float_as_uint(a);
  unsigned int ub = __float_as_uint(b);
  ua = (ua + 0x7FFFu + ((ua >> 16) & 1u)) >> 16;  // RNE f32->bf16
  ub = (ub + 0x7FFFu + ((ub >> 16) & 1u)) >> 16;
  return ua | (ub << 16);
}

static __device__ __forceinline__ unsigned int cvtpk(float a, float b) {
  unsigned int r;
  asm("v_cvt_pk_bf16_f32 %0, %1, %2" : "=v"(r) : "v"(a), "v"(b));
  return r;
}

// meta layout (unsigned int):
// [0..15] cnt | [16..31] off | [32..47] cursor | [48..64] unused here

__global__ void zero_meta_kernel(unsigned int* meta) {
  if (threadIdx.x < 128) meta[threadIdx.x] = 0;
}

__global__ void hist_kernel(const int* __restrict__ idx, int N,
                            unsigned int* __restrict__ meta) {
  __shared__ unsigned int h[NTYPES];
  if (threadIdx.x < NTYPES) h[threadIdx.x] = 0;
  __syncthreads();
  for (int n = blockIdx.x * 256 + threadIdx.x; n < N; n += gridDim.x * 256)
    atomicAdd(&h[idx[n] & 15], 1u);
  __syncthreads();
  if (threadIdx.x < NTYPES) atomicAdd(&meta[threadIdx.x], h[threadIdx.x]);
}

__global__ void prefix_kernel(unsigned int* meta) {
  if (threadIdx.x == 0) {
    unsigned int o = 0;
    for (int t = 0; t < NTYPES; t++) {
      meta[16 + t] = o;
      meta[32 + t] = o;
      o += meta[t];
    }
  }
}

__global__ void scatter_kernel(const int* __restrict__ idx, int N,
                               unsigned int* __restrict__ meta,
                               int* __restrict__ perm) {
  __shared__ unsigned int h[NTYPES];
  __shared__ unsigned int base[NTYPES];
  int b0 = blockIdx.x * 4096;
  if (threadIdx.x < NTYPES) h[threadIdx.x] = 0;
  __syncthreads();
  unsigned int lr[16];
  int tt[16];
#pragma unroll
  for (int i = 0; i < 16; i++) {
    int n = b0 + i * 256 + threadIdx.x;
    int t = (n < N) ? (idx[n] & 15) : 0;
    tt[i] = t;
    lr[i] = (n < N) ? atomicAdd(&h[t], 1u) : 0u;
  }
  __syncthreads();
  if (threadIdx.x < NTYPES)
    base[threadIdx.x] = atomicAdd(&meta[32 + threadIdx.x], h[threadIdx.x]);
  __syncthreads();
#pragma unroll
  for (int i = 0; i < 16; i++) {
    int n = b0 + i * 256 + threadIdx.x;
    if (n < N) perm[base[tt[i]] + lr[i]] = n;
  }
}

// Pack W[t][k][c] (fp32) -> Wp[(t*8+kblk)*256 + c][ks] (bf16), ks = k in
// 32-block. 64B per (kblk, c) -- the MFMA B-fragment unit.
__global__ void packW_kernel(const float* __restrict__ W,
                             unsigned short* __restrict__ Wp) {
  int id = blockIdx.x * 256 + threadIdx.x;  // (t*8+kblk)*256 + c
  int c = id & 255;
  int tk = id >> 8;
  const float* src = W + (size_t)tk * 32 * 256 + c;
  unsigned int buf[16];
#pragma unroll
  for (int p = 0; p < 16; p++)
    buf[p] = f2bf_pk(src[(2 * p) * 256], src[(2 * p + 1) * 256]);
  uint4* d4 = (uint4*)(Wp + (size_t)id * 32);
#pragma unroll
  for (int p = 0; p < 4; p++)
    d4[p] = make_uint4(buf[4 * p], buf[4 * p + 1], buf[4 * p + 2], buf[4 * p + 3]);
}

// Barrier-free grouped GEMM. Block b: type t=b>>4, slice s=b&15 of that
// type's 16-row tiles. W panel in LDS: frag f=kk*16+fn stored at
// Wlds4[f*64 + lane] (lanes contiguous -> conflict-free ds_read_b128).
// Each wave: independent tile stream (j = lo+w, step 8), per-wave pipeline:
//   [loads(t+1) issued] -> K-loop (LDS W + MFMA) -> 64 stores ->
//   s_waitcnt vmcnt(48)  (21 loads + 64 stores queued; newest-48 are all
//   stores -> loads for t+1 provably retired; no barrier, no drain).
__global__ __launch_bounds__(512, 2) void gemm_kernel(
    const float* __restrict__ x, const unsigned short* __restrict__ Wp,
    const int* __restrict__ perm, const unsigned int* __restrict__ meta,
    float* __restrict__ out, float* __restrict__ dump, int N) {
  __shared__ uint4 Wlds4[8192];  // 128 KiB

  int b = blockIdx.x;
  int t = b >> 4;
  int s = b & 15;
  unsigned int off = meta[16 + t];
  unsigned int cnt = meta[t];

  int tid = threadIdx.x;
  int l = tid & 63, w = tid >> 6;
  int lm = l & 15, lh = l >> 4;

  // --- W panel -> LDS, conflict-free fragment layout ---
  const uint4* Wp4 = (const uint4*)Wp;
  for (int f = w; f < 128; f += 8) {
    int kk = f >> 4, fn = f & 15;
    Wlds4[f * 64 + l] =
        Wp4[(size_t)((t * 8 + kk) * 256 + fn * 16 + lm) * 4 + lh];
  }
  __syncthreads();  // only barrier in the kernel

  int Tt = (int)((cnt + 15u) >> 4);  // tiles of this type
  int lo = (s * Tt) >> 4;
  int hi = ((s + 1) * Tt) >> 4;

  int nmask = N - 1;  // N is a power of two; sanitize any garbage perm
  float* dumpP = dump + (size_t)tid * 4;

  int j = lo + w;  // this wave's first tile
  if (j >= hi) return;

  float4 xb[16];
  int prow, ps0, ps1, ps2, ps3;
  {  // prologue: loads for tile j
    unsigned int rowbase = off + (unsigned)j * 16u;
    prow = perm[rowbase + lm] & nmask;
    ps0 = perm[rowbase + lh * 4 + 0];
    ps1 = perm[rowbase + lh * 4 + 1];
    ps2 = perm[rowbase + lh * 4 + 2];
    ps3 = perm[rowbase + lh * 4 + 3];
    const float4* xr = (const float4*)x + (size_t)prow * 64 + lh * 2;
#pragma unroll
    for (int kk = 0; kk < 8; kk++) {
      xb[2 * kk] = xr[kk * 8];
      xb[2 * kk + 1] = xr[kk * 8 + 1];
    }
  }
  asm volatile("s_waitcnt vmcnt(0)" ::: "memory");

  for (; j < hi; j += 8) {
    int rem = (int)cnt - j * 16;
    int nrows = rem < 16 ? rem : 16;
    int myps[4];
    myps[0] = ps0 & nmask;
    myps[1] = ps1 & nmask;
    myps[2] = ps2 & nmask;
    myps[3] = ps3 & nmask;

    // convert A fragments (frees xb for the next tile's loads)
    bf16x8 afr[8];
#pragma unroll
    for (int kk = 0; kk < 8; kk++) {
      uint4 v;
      v.x = cvtpk(xb[2 * kk].x, xb[2 * kk].y);
      v.y = cvtpk(xb[2 * kk].z, xb[2 * kk].w);
      v.z = cvtpk(xb[2 * kk + 1].x, xb[2 * kk + 1].y);
      v.w = cvtpk(xb[2 * kk + 1].z, xb[2 * kk + 1].w);
      afr[kk] = __builtin_bit_cast(bf16x8, v);
    }

    // issue next tile's loads (21 vmem ops; in flight across K-loop+stores)
    int jn = j + 8;
    if (jn < hi) {
      unsigned int rowbase = off + (unsigned)jn * 16u;
      prow = perm[rowbase + lm] & nmask;
      ps0 = perm[rowbase + lh * 4 + 0];
      ps1 = perm[rowbase + lh * 4 + 1];
      ps2 = perm[rowbase + lh * 4 + 2];
      ps3 = perm[rowbase + lh * 4 + 3];
      const float4* xr = (const float4*)x + (size_t)prow * 64 + lh * 2;
#pragma unroll
      for (int kk = 0; kk < 8; kk++) {
        xb[2 * kk] = xr[kk * 8];
        xb[2 * kk + 1] = xr[kk * 8 + 1];
      }
    }
    __builtin_amdgcn_sched_barrier(0);

    // K-loop: LDS W-frags (conflict-free) + MFMA; no vmem
    f32x4 acc[16];
#pragma unroll
    for (int fn = 0; fn < 16; fn++) acc[fn] = (f32x4){0.f, 0.f, 0.f, 0.f};
#pragma unroll
    for (int kk = 0; kk < 8; kk++) {
#pragma unroll
      for (int fn = 0; fn < 16; fn++) {
        bf16x8 bb = __builtin_bit_cast(bf16x8, Wlds4[(kk * 16 + fn) * 64 + l]);
        acc[fn] = __builtin_amdgcn_mfma_f32_16x16x32_bf16(afr[kk], bb,
                                                          acc[fn], 0, 0, 0);
      }
    }

    // stores: 64 dwords; D layout col=lane&15, row=(lane>>4)*4+r_
#pragma unroll
    for (int fn = 0; fn < 16; fn++) {
#pragma unroll
      for (int r_ = 0; r_ < 4; r_++) {
        int rit = lh * 4 + r_;
        bool valid = rit < nrows;
        float* p = valid
                       ? out + (size_t)myps[r_] * 256 + fn * 16 + lm
                       : dumpP + r_;
        *p = acc[fn][r_];
      }
    }

    // per-wave guard: newest 48 outstanding are stores -> next tile's
    // loads retired. No barrier.
    asm volatile("s_waitcnt vmcnt(48)" ::: "memory");
  }
}

extern "C" void kernel_launch(void* const* d_in, const int* in_sizes, int n_in,
                              void* d_out, int out_size, void* d_ws,
                              size_t ws_size, hipStream_t stream) {
  const float* x = (const float*)d_in[0];
  const int* idx = (const int*)d_in[1];
  const float* W = (const float*)d_in[2];
  float* out = (float*)d_out;
  int N = in_sizes[0] / 256;

  // ws: meta 512B | dump 64KB | perm N*4 (+128 pad) | Wp 2MB
  unsigned int* meta = (unsigned int*)d_ws;
  float* dump = (float*)((char*)d_ws + 512);
  int* perm = (int*)((char*)d_ws + 512 + 65536);
  unsigned short* Wp =
      (unsigned short*)((char*)d_ws + 512 + 65536 + (size_t)N * 4 + 128);

  zero_meta_kernel<<<1, 128, 0, stream>>>(meta);
  hist_kernel<<<256, 256, 0, stream>>>(idx, N, meta);
  prefix_kernel<<<1, 64, 0, stream>>>(meta);
  packW_kernel<<<128, 256, 0, stream>>>(W, Wp);
  int nScatter = (N + 4095) / 4096;
  scatter_kernel<<<nScatter, 256, 0, stream>>>(idx, N, meta, perm);

  gemm_kernel<<<GRID_BLOCKS, 512, 0, stream>>>(x, Wp, perm, meta, out, dump,
                                               N);
}